// Round 1
// baseline (1406.045 us; speedup 1.0000x reference)
//
#include <hip/hip_runtime.h>
#include <math.h>

#define N_NODES 100000
#define N_EDGES 1600000
#define NODE_F  64
#define IN_DIM  160
#define ZSTRIDE 164   // floats per z-row in LDS: 16B-aligned rows, padded

// ---------------------------------------------------------------------------
// Phase 1: per-edge gated MLP + atomic scatter-add into msg (= d_out).
// Block = 256 threads (4 waves) handles 64 edges. Each wave computes 16 edges
// x 64 features (lane = feature). K blocked by 8 with W_f/W_s slice held in
// registers, reused across the wave's 16 edges; z read from LDS as broadcast
// float4 (same address across lanes -> LDS broadcast, conflict-free).
// ---------------------------------------------------------------------------
__global__ __launch_bounds__(256) void edge_kernel(
    const float* __restrict__ node_attrs,
    const int*   __restrict__ edge_src,
    const int*   __restrict__ edge_tgt,
    const float* __restrict__ edge_attrs,
    const float* __restrict__ W_f, const float* __restrict__ b_f,
    const float* __restrict__ W_s, const float* __restrict__ b_s,
    float* __restrict__ msg)
{
    __shared__ __align__(16) float zbuf[64 * ZSTRIDE];
    const int tid  = threadIdx.x;
    const int wave = tid >> 6;
    const int lane = tid & 63;
    const int e0   = blockIdx.x * 64;

    // Stage 128 node rows (64 edges x {src,tgt}); one wave loads one 64-f32 row.
    for (int r = wave; r < 128; r += 4) {
        const int el = r >> 1;
        const int e  = e0 + el;
        const int node = (r & 1) ? edge_tgt[e] : edge_src[e];
        zbuf[el * ZSTRIDE + (r & 1) * 64 + lane] = node_attrs[node * 64 + lane];
    }
    // Stage 64 edge-attr rows (32 f32 each); one wave loads 2 rows (contiguous 256B).
    for (int r = wave; r < 32; r += 4) {
        const int el  = r * 2 + (lane >> 5);
        const int col = lane & 31;
        zbuf[el * ZSTRIDE + 128 + col] = edge_attrs[(e0 + el) * 32 + col];
    }
    __syncthreads();

    const int me0 = wave * 16;
    float accf[16], accs[16];
    const float bf = b_f[lane];
    const float bs = b_s[lane];
#pragma unroll
    for (int m = 0; m < 16; ++m) { accf[m] = bf; accs[m] = bs; }

    for (int k0 = 0; k0 < IN_DIM; k0 += 8) {
        float wf[8], ws[8];
#pragma unroll
        for (int j = 0; j < 8; ++j) {
            wf[j] = W_f[(k0 + j) * 64 + lane];
            ws[j] = W_s[(k0 + j) * 64 + lane];
        }
#pragma unroll
        for (int m = 0; m < 16; ++m) {
            const float* zr = &zbuf[(me0 + m) * ZSTRIDE + k0];
            const float4 za = *(const float4*)(zr);
            const float4 zb = *(const float4*)(zr + 4);
            accf[m] = fmaf(za.x, wf[0], accf[m]);
            accf[m] = fmaf(za.y, wf[1], accf[m]);
            accf[m] = fmaf(za.z, wf[2], accf[m]);
            accf[m] = fmaf(za.w, wf[3], accf[m]);
            accf[m] = fmaf(zb.x, wf[4], accf[m]);
            accf[m] = fmaf(zb.y, wf[5], accf[m]);
            accf[m] = fmaf(zb.z, wf[6], accf[m]);
            accf[m] = fmaf(zb.w, wf[7], accf[m]);
            accs[m] = fmaf(za.x, ws[0], accs[m]);
            accs[m] = fmaf(za.y, ws[1], accs[m]);
            accs[m] = fmaf(za.z, ws[2], accs[m]);
            accs[m] = fmaf(za.w, ws[3], accs[m]);
            accs[m] = fmaf(zb.x, ws[4], accs[m]);
            accs[m] = fmaf(zb.y, ws[5], accs[m]);
            accs[m] = fmaf(zb.z, ws[6], accs[m]);
            accs[m] = fmaf(zb.w, ws[7], accs[m]);
        }
    }

    // Gated activation + scatter-add: h = sigmoid(f) * softplus(s)
#pragma unroll
    for (int m = 0; m < 16; ++m) {
        const float xf = accf[m];
        const float xs = accs[m];
        const float sig = 1.0f / (1.0f + __expf(-xf));
        const float sp  = fmaxf(xs, 0.0f) + logf(1.0f + __expf(-fabsf(xs)));
        const float h   = sig * sp;
        const int e = e0 + me0 + m;
        atomicAdd(&msg[edge_src[e] * 64 + lane], h);
    }
}

// ---------------------------------------------------------------------------
// Phase 2: per-feature sum / sumsq over nodes (for BatchNorm batch stats).
// stats[0:64] = sum, stats[64:128] = sum of squares.
// ---------------------------------------------------------------------------
#define STATS_BLOCKS 200
__global__ __launch_bounds__(256) void stats_kernel(
    const float* __restrict__ msg, float* __restrict__ stats)
{
    const int tid = threadIdx.x;
    const int f = tid & 63;
    const int g = tid >> 6;
    float s = 0.0f, q = 0.0f;
    for (int r = blockIdx.x * 4 + g; r < N_NODES; r += STATS_BLOCKS * 4) {
        const float v = msg[r * 64 + f];
        s += v;
        q = fmaf(v, v, q);
    }
    __shared__ float rs[4][64];
    __shared__ float rq[4][64];
    rs[g][f] = s;
    rq[g][f] = q;
    __syncthreads();
    if (tid < 64) {
        const float ss = rs[0][f] + rs[1][f] + rs[2][f] + rs[3][f];
        const float qq = rq[0][f] + rq[1][f] + rq[2][f] + rq[3][f];
        atomicAdd(&stats[f], ss);
        atomicAdd(&stats[64 + f], qq);
    }
}

// ---------------------------------------------------------------------------
// Phase 3: in-place BN (training stats, biased var) + residual.
// out currently holds msg; out = node_attrs + (msg-mean)*rsqrt(var+eps)*gamma+beta
// ---------------------------------------------------------------------------
__global__ __launch_bounds__(256) void norm_kernel(
    const float* __restrict__ node_attrs,
    const float* __restrict__ stats,
    const float* __restrict__ gamma,
    const float* __restrict__ beta,
    float* __restrict__ out)
{
    const int i = blockIdx.x * blockDim.x + threadIdx.x;
    const int idx = i * 4;
    if (idx >= N_NODES * 64) return;
    const int f = idx & 63;   // 64 % 4 == 0 -> f..f+3 same row
    const float inv_n = 1.0f / (float)N_NODES;

    const float4 m4 = *(const float4*)&out[idx];
    const float4 x4 = *(const float4*)&node_attrs[idx];

    float mean[4], rstd[4], gm[4], bt[4];
#pragma unroll
    for (int j = 0; j < 4; ++j) {
        mean[j] = stats[f + j] * inv_n;
        const float var = stats[64 + f + j] * inv_n - mean[j] * mean[j];
        rstd[j] = rsqrtf(var + 1e-5f);
        gm[j] = gamma[f + j];
        bt[j] = beta[f + j];
    }
    float4 o;
    o.x = x4.x + (m4.x - mean[0]) * rstd[0] * gm[0] + bt[0];
    o.y = x4.y + (m4.y - mean[1]) * rstd[1] * gm[1] + bt[1];
    o.z = x4.z + (m4.z - mean[2]) * rstd[2] * gm[2] + bt[2];
    o.w = x4.w + (m4.w - mean[3]) * rstd[3] * gm[3] + bt[3];
    *(float4*)&out[idx] = o;
}

extern "C" void kernel_launch(void* const* d_in, const int* in_sizes, int n_in,
                              void* d_out, int out_size, void* d_ws, size_t ws_size,
                              hipStream_t stream)
{
    const float* node_attrs = (const float*)d_in[0];
    const int*   edge_index = (const int*)d_in[1];   // [2, E] int32
    const float* edge_attrs = (const float*)d_in[2];
    const float* W_f   = (const float*)d_in[3];
    const float* b_f   = (const float*)d_in[4];
    const float* W_s   = (const float*)d_in[5];
    const float* b_s   = (const float*)d_in[6];
    const float* gamma = (const float*)d_in[7];
    const float* beta  = (const float*)d_in[8];

    float* out   = (float*)d_out;          // doubles as the msg accumulator
    float* stats = (float*)d_ws;           // 128 floats

    const int* edge_src = edge_index;
    const int* edge_tgt = edge_index + N_EDGES;

    hipMemsetAsync(out, 0, (size_t)N_NODES * NODE_F * sizeof(float), stream);
    hipMemsetAsync(stats, 0, 128 * sizeof(float), stream);

    edge_kernel<<<N_EDGES / 64, 256, 0, stream>>>(
        node_attrs, edge_src, edge_tgt, edge_attrs, W_f, b_f, W_s, b_s, out);

    stats_kernel<<<STATS_BLOCKS, 256, 0, stream>>>(out, stats);

    norm_kernel<<<(N_NODES * NODE_F / 4 + 255) / 256, 256, 0, stream>>>(
        node_attrs, stats, gamma, beta, out);
}

// Round 2
// 838.881 us; speedup vs baseline: 1.6761x; 1.6761x over previous
//
#include <hip/hip_runtime.h>
#include <math.h>

#define N_NODES 100000
#define N_EDGES 1600000
#define NODE_F  64
#define IN_DIM  160          // 2*64 + 32
#define N_TILES 25000        // N_EDGES / 64
#define ZSTRIDE 168          // bf16 elems per z-row in LDS (336 B: 16B-aligned, odd*4 dwords)
#define EDGE_GRID 1024

typedef __attribute__((ext_vector_type(8))) short short8;   // 8 bf16 = 4 VGPRs
typedef __attribute__((ext_vector_type(4))) float f32x4;

// round-to-nearest-even f32 -> bf16 bits (inputs are finite)
static __device__ inline unsigned short f2bf(float f) {
    union { float f; unsigned u; } v; v.f = f;
    unsigned r = v.u + 0x7fffu + ((v.u >> 16) & 1u);
    return (unsigned short)(r >> 16);
}
static __device__ inline unsigned pack2(float lo, float hi) {
    return (unsigned)f2bf(lo) | ((unsigned)f2bf(hi) << 16);
}

// ---------------------------------------------------------------------------
// Phase 1: gather -> bf16 z-tile in LDS -> MFMA gated MLP -> atomic scatter.
// Block = 256 thr (4 waves). Per tile: 64 edges. Wave w owns feature slice
// [16w, 16w+16) for BOTH matrices; W fragments live in registers (loaded once
// per block via a 21.5 KB LDS staging pass, reused for all ~25 tiles/block).
// ---------------------------------------------------------------------------
__global__ __launch_bounds__(256, 4) void edge_kernel(
    const float* __restrict__ node_attrs,
    const int*   __restrict__ edge_src,
    const int*   __restrict__ edge_tgt,
    const float* __restrict__ edge_attrs,
    const float* __restrict__ W_f, const float* __restrict__ b_f,
    const float* __restrict__ W_s, const float* __restrict__ b_s,
    float* __restrict__ msg)
{
    __shared__ __align__(16) short sbuf[64 * ZSTRIDE];   // 21504 B; W-stage / z-tile union
    unsigned* sbuf32 = (unsigned*)sbuf;

    const int tid  = threadIdx.x;
    const int wave = tid >> 6;
    const int lane = tid & 63;
    const int quad = lane >> 4;       // 0..3
    const int l15  = lane & 15;
    const int half = lane >> 5;       // 0..1
    const int l31  = lane & 31;

    // ---- Stage W_f then W_s transposed to LDS, pull B-fragments to registers.
    short8 bF[5], bS[5];
#pragma unroll
    for (int mat = 0; mat < 2; ++mat) {
        const float* W = mat ? W_s : W_f;
        __syncthreads();
        for (int idx = tid; idx < IN_DIM * 64; idx += 256) {
            const int k = idx >> 6, n = idx & 63;
            sbuf[n * ZSTRIDE + k] = (short)f2bf(W[idx]);
        }
        __syncthreads();
        // B-frag for n-tile `wave`: lane holds Wt[16*wave + l15][kc*32 + quad*8 + j]
#pragma unroll
        for (int kc = 0; kc < 5; ++kc) {
            const short8 b = *(const short8*)&sbuf[(16 * wave + l15) * ZSTRIDE + kc * 32 + quad * 8];
            if (mat) bS[kc] = b; else bF[kc] = b;
        }
    }

    const float bias_f = b_f[16 * wave + l15];
    const float bias_s = b_s[16 * wave + l15];

    for (int t = blockIdx.x; t < N_TILES; t += EDGE_GRID) {
        const int e0 = t * 64;
        __syncthreads();   // protect sbuf from previous iteration's readers

        // ---- Stage z[64][160] as bf16. Node parts: wave w does edges [16w,16w+16);
        // half-wave 0 = x_i (src), half-wave 1 = x_j (tgt); lane covers 2 floats.
        for (int rr = 0; rr < 16; ++rr) {
            const int el = 16 * wave + rr;
            const int e  = e0 + el;
            const int node = half ? edge_tgt[e] : edge_src[e];
            const float2 v = *(const float2*)&node_attrs[node * 64 + l31 * 2];
            sbuf32[el * (ZSTRIDE / 2) + half * 32 + l31] = pack2(v.x, v.y);
        }
        // Edge attrs: 64 edges x 16 float2, linear across block.
#pragma unroll
        for (int i = 0; i < 8; ++i) {
            const int p  = tid + i * 256;        // 0..2047
            const int el = p >> 4, off2 = p & 15;
            const float2 v = *(const float2*)&edge_attrs[(size_t)(e0 + el) * 32 + off2 * 2];
            sbuf32[el * (ZSTRIDE / 2) + 64 + off2] = pack2(v.x, v.y);
        }
        __syncthreads();

        // ---- MFMA: 4 m-tiles x 5 k-chunks x 2 matrices
#pragma unroll
        for (int mt = 0; mt < 4; ++mt) {
            f32x4 accF = {0.f, 0.f, 0.f, 0.f};
            f32x4 accS = {0.f, 0.f, 0.f, 0.f};
#pragma unroll
            for (int kc = 0; kc < 5; ++kc) {
                const short8 a = *(const short8*)&sbuf[(mt * 16 + l15) * ZSTRIDE + kc * 32 + quad * 8];
                accF = __builtin_amdgcn_mfma_f32_16x16x32_bf16(a, bF[kc], accF, 0, 0, 0);
                accS = __builtin_amdgcn_mfma_f32_16x16x32_bf16(a, bS[kc], accS, 0, 0, 0);
            }
            // C/D: col = l15 (feature within slice), row = quad*4 + r (edge in tile)
#pragma unroll
            for (int r = 0; r < 4; ++r) {
                const float xf = accF[r] + bias_f;
                const float xs = accS[r] + bias_s;
                const float sig = 1.0f / (1.0f + __expf(-xf));
                const float sp  = fmaxf(xs, 0.0f) + log1pf(__expf(-fabsf(xs)));
                const float h   = sig * sp;
                const int e = e0 + mt * 16 + quad * 4 + r;
                atomicAdd(&msg[(size_t)edge_src[e] * 64 + 16 * wave + l15], h);
            }
        }
    }
}

// ---------------------------------------------------------------------------
// Phase 2: per-feature sum / sumsq over nodes (BatchNorm batch stats).
// ---------------------------------------------------------------------------
#define STATS_BLOCKS 200
__global__ __launch_bounds__(256) void stats_kernel(
    const float* __restrict__ msg, float* __restrict__ stats)
{
    const int tid = threadIdx.x;
    const int f = tid & 63;
    const int g = tid >> 6;
    float s = 0.0f, q = 0.0f;
    for (int r = blockIdx.x * 4 + g; r < N_NODES; r += STATS_BLOCKS * 4) {
        const float v = msg[r * 64 + f];
        s += v;
        q = fmaf(v, v, q);
    }
    __shared__ float rs[4][64];
    __shared__ float rq[4][64];
    rs[g][f] = s;
    rq[g][f] = q;
    __syncthreads();
    if (tid < 64) {
        const float ss = rs[0][f] + rs[1][f] + rs[2][f] + rs[3][f];
        const float qq = rq[0][f] + rq[1][f] + rq[2][f] + rq[3][f];
        atomicAdd(&stats[f], ss);
        atomicAdd(&stats[64 + f], qq);
    }
}

// ---------------------------------------------------------------------------
// Phase 3: in-place BN (training stats, biased var) + residual.
// ---------------------------------------------------------------------------
__global__ __launch_bounds__(256) void norm_kernel(
    const float* __restrict__ node_attrs,
    const float* __restrict__ stats,
    const float* __restrict__ gamma,
    const float* __restrict__ beta,
    float* __restrict__ out)
{
    const int i = blockIdx.x * blockDim.x + threadIdx.x;
    const int idx = i * 4;
    if (idx >= N_NODES * 64) return;
    const int f = idx & 63;
    const float inv_n = 1.0f / (float)N_NODES;

    const float4 m4 = *(const float4*)&out[idx];
    const float4 x4 = *(const float4*)&node_attrs[idx];

    float mean[4], rstd[4], gm[4], bt[4];
#pragma unroll
    for (int j = 0; j < 4; ++j) {
        mean[j] = stats[f + j] * inv_n;
        const float var = stats[64 + f + j] * inv_n - mean[j] * mean[j];
        rstd[j] = rsqrtf(var + 1e-5f);
        gm[j] = gamma[f + j];
        bt[j] = beta[f + j];
    }
    float4 o;
    o.x = x4.x + (m4.x - mean[0]) * rstd[0] * gm[0] + bt[0];
    o.y = x4.y + (m4.y - mean[1]) * rstd[1] * gm[1] + bt[1];
    o.z = x4.z + (m4.z - mean[2]) * rstd[2] * gm[2] + bt[2];
    o.w = x4.w + (m4.w - mean[3]) * rstd[3] * gm[3] + bt[3];
    *(float4*)&out[idx] = o;
}

extern "C" void kernel_launch(void* const* d_in, const int* in_sizes, int n_in,
                              void* d_out, int out_size, void* d_ws, size_t ws_size,
                              hipStream_t stream)
{
    const float* node_attrs = (const float*)d_in[0];
    const int*   edge_index = (const int*)d_in[1];   // [2, E] int32
    const float* edge_attrs = (const float*)d_in[2];
    const float* W_f   = (const float*)d_in[3];
    const float* b_f   = (const float*)d_in[4];
    const float* W_s   = (const float*)d_in[5];
    const float* b_s   = (const float*)d_in[6];
    const float* gamma = (const float*)d_in[7];
    const float* beta  = (const float*)d_in[8];

    float* out   = (float*)d_out;          // doubles as the msg accumulator
    float* stats = (float*)d_ws;           // 128 floats

    const int* edge_src = edge_index;
    const int* edge_tgt = edge_index + N_EDGES;

    hipMemsetAsync(out, 0, (size_t)N_NODES * NODE_F * sizeof(float), stream);
    hipMemsetAsync(stats, 0, 128 * sizeof(float), stream);

    edge_kernel<<<EDGE_GRID, 256, 0, stream>>>(
        node_attrs, edge_src, edge_tgt, edge_attrs, W_f, b_f, W_s, b_s, out);

    stats_kernel<<<STATS_BLOCKS, 256, 0, stream>>>(out, stats);

    norm_kernel<<<(N_NODES * NODE_F / 4 + 255) / 256, 256, 0, stream>>>(
        node_attrs, stats, gamma, beta, out);
}

// Round 4
// 630.070 us; speedup vs baseline: 2.2316x; 1.3314x over previous
//
#include <hip/hip_runtime.h>
#include <math.h>

#define N_NODES 100000
#define N_EDGES 1600000
#define NODE_F  64
#define IN_DIM  160          // 2*64 + 32
#define N_TILES 25000        // N_EDGES / 64
#define ZSTRIDE 168          // bf16 elems per z-row in LDS (336 B, 16B-aligned)
#define EDGE_GRID 1536       // 6 blocks/CU

typedef __attribute__((ext_vector_type(8))) short short8;   // 8 bf16 = 4 VGPRs
typedef __attribute__((ext_vector_type(4))) float f32x4;

// round-to-nearest-even f32 -> bf16 bits (scalar; used only in W staging)
static __device__ inline unsigned short f2bf(float f) {
    union { float f; unsigned u; } v; v.f = f;
    unsigned r = v.u + 0x7fffu + ((v.u >> 16) & 1u);
    return (unsigned short)(r >> 16);
}

// RNE-round two f32 and pack their high halves into one dword:
// per float: round-bias add; then one v_perm_b32 grabs both high16s.
static __device__ inline unsigned pack2(float lo, float hi) {
    union { float f; unsigned u; } a, b; a.f = lo; b.f = hi;
    const unsigned ra = a.u + 0x7fffu + ((a.u >> 16) & 1u);
    const unsigned rb = b.u + 0x7fffu + ((b.u >> 16) & 1u);
    // result byte0,1 = ra bytes 2,3 ; byte2,3 = rb bytes 2,3
    return __builtin_amdgcn_perm(rb, ra, 0x07060302u);
}

// ---------------------------------------------------------------------------
// Phase 1: gather f32 node rows -> bf16 z-tile in LDS -> MFMA gated MLP ->
// atomic scatter. Block = 256 thr (4 waves), 64 edges/tile. Wave w owns
// features [16w,16w+16) of both matrices; W frags in registers (loaded once
// per block). Tile edge indices live in registers, distributed via __shfl;
// next tile's indices are prefetched to hide gather-index latency.
// ---------------------------------------------------------------------------
__global__ __launch_bounds__(256, 6) void edge_kernel(
    const float* __restrict__ node_attrs,
    const int*   __restrict__ edge_src,
    const int*   __restrict__ edge_tgt,
    const float* __restrict__ edge_attrs,
    const float* __restrict__ W_f, const float* __restrict__ b_f,
    const float* __restrict__ W_s, const float* __restrict__ b_s,
    float* __restrict__ msg)
{
    __shared__ __align__(16) short sbuf[64 * ZSTRIDE];   // 21504 B
    unsigned* sbuf32 = (unsigned*)sbuf;

    const int tid  = threadIdx.x;
    const int wave = tid >> 6;
    const int lane = tid & 63;
    const int quad = lane >> 4;       // 0..3
    const int l15  = lane & 15;

    // ---- Stage W_f then W_s transposed to LDS, pull B-fragments to registers.
    short8 bF[5], bS[5];
#pragma unroll
    for (int mat = 0; mat < 2; ++mat) {
        const float* W = mat ? W_s : W_f;
        __syncthreads();
        for (int idx = tid; idx < IN_DIM * 64; idx += 256) {
            const int k = idx >> 6, n = idx & 63;
            sbuf[n * ZSTRIDE + k] = (short)f2bf(W[idx]);
        }
        __syncthreads();
#pragma unroll
        for (int kc = 0; kc < 5; ++kc) {
            const short8 b = *(const short8*)&sbuf[(16 * wave + l15) * ZSTRIDE + kc * 32 + quad * 8];
            if (mat) bS[kc] = b; else bF[kc] = b;
        }
    }

    const float bias_f = b_f[16 * wave + l15];
    const float bias_s = b_s[16 * wave + l15];
    float* const msgf  = msg + 16 * wave + l15;   // per-lane feature column

    // Prefetch first tile's indices.
    int srcv = edge_src[blockIdx.x * 64 + lane];
    int tgtv = edge_tgt[blockIdx.x * 64 + lane];

    for (int t = blockIdx.x; t < N_TILES; t += EDGE_GRID) {
        const int e0 = t * 64;

        __syncthreads();   // protect sbuf from previous iteration's readers

        // ---- Node rows (f32 -> bf16 inline): wave w stages edges [16w,16w+16).
        // iter i: 4 row-halves; half = quad&1 (0=src,1=tgt), el = i*2+(quad>>1).
#pragma unroll
        for (int i = 0; i < 8; ++i) {
            const int el   = i * 2 + (quad >> 1);
            const int half = quad & 1;
            const int sl   = 16 * wave + el;
            const int ns   = __shfl(srcv, sl);
            const int nt   = __shfl(tgtv, sl);
            const int node = half ? nt : ns;
            const float4 v = *(const float4*)&node_attrs[node * 64 + l15 * 4];
            uint2 o; o.x = pack2(v.x, v.y); o.y = pack2(v.z, v.w);
            *(uint2*)&sbuf32[sl * (ZSTRIDE / 2) + half * 32 + l15 * 2] = o;
        }
        // ---- Edge attrs (f32 -> bf16 inline): 2 iters x 4 floats/thread... (8 total)
#pragma unroll
        for (int i = 0; i < 2; ++i) {
            const int p  = i * 256 + tid;       // 0..511
            const int el = p >> 3, g = p & 7;
            const float4 v = *(const float4*)&edge_attrs[(size_t)(e0 + el) * 32 + g * 4];
            uint2 o; o.x = pack2(v.x, v.y); o.y = pack2(v.z, v.w);
            *(uint2*)&sbuf32[el * (ZSTRIDE / 2) + 64 + g * 2] = o;
        }

        // Prefetch next tile's indices (loads overlap the MFMA section).
        const int tn = t + EDGE_GRID;
        int nsrc = 0, ntgt = 0;
        if (tn < N_TILES) {
            nsrc = edge_src[tn * 64 + lane];
            ntgt = edge_tgt[tn * 64 + lane];
        }
        __syncthreads();

        // ---- MFMA: 4 m-tiles x 5 k-chunks x 2 matrices, then fused epilogue.
#pragma unroll
        for (int mt = 0; mt < 4; ++mt) {
            f32x4 accF = {0.f, 0.f, 0.f, 0.f};
            f32x4 accS = {0.f, 0.f, 0.f, 0.f};
#pragma unroll
            for (int kc = 0; kc < 5; ++kc) {
                const short8 a = *(const short8*)&sbuf[(mt * 16 + l15) * ZSTRIDE + kc * 32 + quad * 8];
                accF = __builtin_amdgcn_mfma_f32_16x16x32_bf16(a, bF[kc], accF, 0, 0, 0);
                accS = __builtin_amdgcn_mfma_f32_16x16x32_bf16(a, bS[kc], accS, 0, 0, 0);
            }
            // C/D: col = l15 (feature), row = quad*4 + r (edge within m-tile)
#pragma unroll
            for (int r = 0; r < 4; ++r) {
                const float xf = accF[r] + bias_f;
                const float xs = accS[r] + bias_s;
                const float sig = __builtin_amdgcn_rcpf(1.0f + __expf(-xf));
                const float sp  = fmaxf(xs, 0.0f) + __logf(1.0f + __expf(-fabsf(xs)));
                const float h   = sig * sp;
                const int sl    = mt * 16 + quad * 4 + r;   // edge within tile
                const int node  = __shfl(srcv, sl);
                atomicAdd(&msgf[node * 64], h);
            }
        }

        srcv = nsrc;
        tgtv = ntgt;
    }
}

// ---------------------------------------------------------------------------
// Phase 2: per-feature sum / sumsq over nodes (BatchNorm batch stats).
// ---------------------------------------------------------------------------
#define STATS_BLOCKS 400
__global__ __launch_bounds__(256) void stats_kernel(
    const float* __restrict__ msg, float* __restrict__ stats)
{
    const int tid = threadIdx.x;
    const int f = tid & 63;
    const int g = tid >> 6;
    float s = 0.0f, q = 0.0f;
    for (int r = blockIdx.x * 4 + g; r < N_NODES; r += STATS_BLOCKS * 4) {
        const float v = msg[r * 64 + f];
        s += v;
        q = fmaf(v, v, q);
    }
    __shared__ float rs[4][64];
    __shared__ float rq[4][64];
    rs[g][f] = s;
    rq[g][f] = q;
    __syncthreads();
    if (tid < 64) {
        const float ss = rs[0][f] + rs[1][f] + rs[2][f] + rs[3][f];
        const float qq = rq[0][f] + rq[1][f] + rq[2][f] + rq[3][f];
        atomicAdd(&stats[f], ss);
        atomicAdd(&stats[64 + f], qq);
    }
}

// ---------------------------------------------------------------------------
// Phase 3: in-place BN (training stats, biased var) + residual.
// ---------------------------------------------------------------------------
__global__ __launch_bounds__(256) void norm_kernel(
    const float* __restrict__ node_attrs,
    const float* __restrict__ stats,
    const float* __restrict__ gamma,
    const float* __restrict__ beta,
    float* __restrict__ out)
{
    const int i = blockIdx.x * blockDim.x + threadIdx.x;
    const int idx = i * 4;
    if (idx >= N_NODES * 64) return;
    const int f = idx & 63;
    const float inv_n = 1.0f / (float)N_NODES;

    const float4 m4 = *(const float4*)&out[idx];
    const float4 x4 = *(const float4*)&node_attrs[idx];

    float mean[4], rstd[4], gm[4], bt[4];
#pragma unroll
    for (int j = 0; j < 4; ++j) {
        mean[j] = stats[f + j] * inv_n;
        const float var = stats[64 + f + j] * inv_n - mean[j] * mean[j];
        rstd[j] = rsqrtf(var + 1e-5f);
        gm[j] = gamma[f + j];
        bt[j] = beta[f + j];
    }
    float4 o;
    o.x = x4.x + (m4.x - mean[0]) * rstd[0] * gm[0] + bt[0];
    o.y = x4.y + (m4.y - mean[1]) * rstd[1] * gm[1] + bt[1];
    o.z = x4.z + (m4.z - mean[2]) * rstd[2] * gm[2] + bt[2];
    o.w = x4.w + (m4.w - mean[3]) * rstd[3] * gm[3] + bt[3];
    *(float4*)&out[idx] = o;
}

extern "C" void kernel_launch(void* const* d_in, const int* in_sizes, int n_in,
                              void* d_out, int out_size, void* d_ws, size_t ws_size,
                              hipStream_t stream)
{
    const float* node_attrs = (const float*)d_in[0];
    const int*   edge_index = (const int*)d_in[1];   // [2, E] int32
    const float* edge_attrs = (const float*)d_in[2];
    const float* W_f   = (const float*)d_in[3];
    const float* b_f   = (const float*)d_in[4];
    const float* W_s   = (const float*)d_in[5];
    const float* b_s   = (const float*)d_in[6];
    const float* gamma = (const float*)d_in[7];
    const float* beta  = (const float*)d_in[8];

    float* out   = (float*)d_out;          // doubles as the msg accumulator
    float* stats = (float*)d_ws;           // 128 floats (512 B of ws only)

    const int* edge_src = edge_index;
    const int* edge_tgt = edge_index + N_EDGES;

    hipMemsetAsync(out, 0, (size_t)N_NODES * NODE_F * sizeof(float), stream);
    hipMemsetAsync(stats, 0, 128 * sizeof(float), stream);

    edge_kernel<<<EDGE_GRID, 256, 0, stream>>>(
        node_attrs, edge_src, edge_tgt, edge_attrs, W_f, b_f, W_s, b_s, out);

    stats_kernel<<<STATS_BLOCKS, 256, 0, stream>>>(out, stats);

    norm_kernel<<<(N_NODES * NODE_F / 4 + 255) / 256, 256, 0, stream>>>(
        node_attrs, stats, gamma, beta, out);
}